// Round 6
// baseline (375.358 us; speedup 1.0000x reference)
//
#include <hip/hip_runtime.h>

typedef short s16x8 __attribute__((ext_vector_type(8)));
typedef float f32x4 __attribute__((ext_vector_type(4)));
typedef unsigned int u32;

#define DEV static __device__ __forceinline__

DEV unsigned short f2bf(float x){
  u32 u = __builtin_bit_cast(u32, x);
  return (unsigned short)((u + 0x7FFFu + ((u >> 16) & 1u)) >> 16);
}
DEV float bf2f(unsigned short h){ u32 u = ((u32)h) << 16; return __builtin_bit_cast(float, u); }
DEV u32 pack2(float a, float b){ return (u32)f2bf(a) | ((u32)f2bf(b) << 16); }

DEV void gld16(const void* g, void* l){
  __builtin_amdgcn_global_load_lds((const __attribute__((address_space(1))) u32*)g,
                                   (__attribute__((address_space(3))) u32*)l, 16, 0, 0);
}

// counted vmcnt wait (T4)
template<int N> DEV void vmwait(){
  static_assert(N>=0 && N<=16, "vmcnt range");
  if constexpr (N==0) asm volatile("s_waitcnt vmcnt(0)" ::: "memory");
  else if constexpr (N==1) asm volatile("s_waitcnt vmcnt(1)" ::: "memory");
  else if constexpr (N==2) asm volatile("s_waitcnt vmcnt(2)" ::: "memory");
  else if constexpr (N==3) asm volatile("s_waitcnt vmcnt(3)" ::: "memory");
  else if constexpr (N==4) asm volatile("s_waitcnt vmcnt(4)" ::: "memory");
  else if constexpr (N==5) asm volatile("s_waitcnt vmcnt(5)" ::: "memory");
  else if constexpr (N==6) asm volatile("s_waitcnt vmcnt(6)" ::: "memory");
  else if constexpr (N==7) asm volatile("s_waitcnt vmcnt(7)" ::: "memory");
  else if constexpr (N==8) asm volatile("s_waitcnt vmcnt(8)" ::: "memory");
  else if constexpr (N==9) asm volatile("s_waitcnt vmcnt(9)" ::: "memory");
  else if constexpr (N==10) asm volatile("s_waitcnt vmcnt(10)" ::: "memory");
  else if constexpr (N==11) asm volatile("s_waitcnt vmcnt(11)" ::: "memory");
  else if constexpr (N==12) asm volatile("s_waitcnt vmcnt(12)" ::: "memory");
  else                      asm volatile("s_waitcnt vmcnt(16)" ::: "memory");
}
DEV void pipebar(){
  __builtin_amdgcn_sched_barrier(0);
  __builtin_amdgcn_s_barrier();
  __builtin_amdgcn_sched_barrier(0);
}
DEV void lgkm0(){ asm volatile("s_waitcnt lgkmcnt(0)" ::: "memory"); }

// ---------------- prep: w1,w2 transpose->bf16 ----------------
__global__ void k_prep(const float* __restrict__ w1, const float* __restrict__ w2,
                       unsigned short* __restrict__ w1t, unsigned short* __restrict__ w2t){
  int idx = blockIdx.x*256 + threadIdx.x;
  if (idx < 512*256){ int r=idx/256, c=idx%256; w1t[(size_t)c*512 + r] = f2bf(w1[idx]); }
  else { int j = idx - 512*256; if (j < 256*64){ int r=j/64, c=j%64; w2t[(size_t)c*256 + r] = f2bf(w2[j]); } }
}

// ------- bf16 staging: global_load_lds 16B, swizzle on GLOBAL src (rule 21) -------
// physical slot s of row r holds source k-chunk s ^ SW(r); SW(r)=(r>>RSH)&SLM.
// RSH=1 for 4-slot rows (BK=32) so banks split on r&1 -> free 2-way.
template<int ROWS,int BK,int THREADS>
DEV void stage_lds(const unsigned short* __restrict__ src, int row0, int ld,
                   int kk, char* lds, int tid){
  constexpr int SLOTS = BK/8, SLM = SLOTS-1, RPC = 64/SLOTS;
  constexpr int RSH = (SLOTS==4) ? 1 : 0;
  constexpr int NCH = ROWS*BK*2/1024;
  constexpr int NW = THREADS/64, NI = NCH/NW;
  static_assert(NI*NW==NCH, "chunk exact");
  const int lane = tid & 63, wid = tid >> 6;
  #pragma unroll
  for (int i=0;i<NI;i++){
    int c = i*NW + wid;
    int r = c*RPC + lane/SLOTS;
    int s = lane & SLM;
    int ks = s ^ ((r>>RSH)&SLM);
    gld16(src + (size_t)(row0+r)*ld + kk + ks*8, lds + c*1024);
  }
}

// ------- f32 staging (T14): load 8-f32 chunks early; cvt(+relu)+ds_write(+WB) late ----
template<int ROWS,int BK,int THREADS,int NC8>
DEV void f32_load(const float* __restrict__ src, int row0, int ld, int kk,
                  float4* regs, int tid){
  constexpr int CPR = BK/8;
  #pragma unroll
  for (int i=0;i<NC8;i++){
    int v = tid + i*THREADS;
    int r = v/CPR, c = v%CPR;
    const float* p = src + (size_t)(row0+r)*ld + kk + c*8;
    regs[2*i]   = *(const float4*)p;
    regs[2*i+1] = *(const float4*)(p+4);
  }
}
template<int ROWS,int BK,int THREADS,int NC8,bool RELU,bool WB>
DEV void f32_write(const float4* regs, char* lds, unsigned short* __restrict__ gdst,
                   int row0, int gld_, int kk, int tid){
  constexpr int CPR = BK/8, SLOTS = BK/8, SLM = SLOTS-1, ROWB = BK*2;
  constexpr int RSH = (SLOTS==4) ? 1 : 0;
  #pragma unroll
  for (int i=0;i<NC8;i++){
    int v = tid + i*THREADS;
    int r = v/CPR, c = v%CPR;
    float4 x = regs[2*i], y = regs[2*i+1];
    if constexpr (RELU){
      x.x=fmaxf(x.x,0.f); x.y=fmaxf(x.y,0.f); x.z=fmaxf(x.z,0.f); x.w=fmaxf(x.w,0.f);
      y.x=fmaxf(y.x,0.f); y.y=fmaxf(y.y,0.f); y.z=fmaxf(y.z,0.f); y.w=fmaxf(y.w,0.f);
    }
    int4 p; p.x=(int)pack2(x.x,x.y); p.y=(int)pack2(x.z,x.w);
            p.z=(int)pack2(y.x,y.y); p.w=(int)pack2(y.z,y.w);
    int s = c ^ ((r>>RSH)&SLM);
    *(int4*)(lds + r*ROWB + s*16) = p;
    if constexpr (WB)
      *(int4*)(gdst + (size_t)(row0+r)*gld_ + kk + c*8) = p;
  }
}

// ---------------- unified pipelined GEMM: C[M,N] = A[M,K] @ Bt[N,K]^T ----------------
// T3+T4: 3 LDS buffers, 2 tiles in flight, counted vmcnt, raw barriers.
// AF32: A is f32 (reg-staged, cvt late). AWB: also write A-tile bf16 to Awb.
// BF32/BRELU: B is f32 (+relu). ATOMIC: f32 atomicAdd epilogue (split-K).
template<int BM,int BN,int BK,int WR,int WC,bool AF32,bool BF32,bool ATOMIC,bool BRELU,bool AWB>
__global__ __launch_bounds__(WR*WC*64, (WR*WC==8)?4:2)
void k_gemm(const void* __restrict__ Ap, const void* __restrict__ Bp,
            void* __restrict__ Cp, unsigned short* __restrict__ Awb,
            int lda, int ldb, int ldc, int kchunk)
{
  constexpr int THREADS = WR*WC*64;
  constexpr int ROWB = BK*2, SLOTS = BK/8, SLM = SLOTS-1;
  constexpr int RSH = (SLOTS==4) ? 1 : 0;
  constexpr int TBYTES = (BM+BN)*ROWB;
  constexpr int WM = BM/WR, WN = BN/WC;
  constexpr int FM = WM/16, FN = WN/16, KS = BK/32;
  constexpr int NC8A = AF32 ? BM*BK/(8*THREADS) : 0;
  constexpr int NC8B = BF32 ? BN*BK/(8*THREADS) : 0;
  constexpr int LAb  = AF32 ? 0 : BM*ROWB/1024/(THREADS/64);
  constexpr int LBb  = BF32 ? 0 : BN*ROWB/1024/(THREADS/64);
  constexpr int L  = 2*NC8A + 2*NC8B + LAb + LBb;
  constexpr int NS = AWB ? NC8A : 0;
  constexpr int MA = AF32 ? 2*NC8A : 1;
  constexpr int MB = BF32 ? 2*NC8B : 1;

  __shared__ char smem[3*TBYTES];

  const int tid = threadIdx.x, lane = tid & 63;
  const int wid = tid >> 6, wrr = wid / WC, wcc = wid % WC;
  const int m0 = blockIdx.y * BM, n0 = blockIdx.x * BN;
  const int kbeg = blockIdx.z * kchunk, nk = kchunk / BK;

  const float* Af = (const float*)Ap;
  const unsigned short* Ah = (const unsigned short*)Ap;
  const float* Bf = (const float*)Bp;
  const unsigned short* Bh = (const unsigned short*)Bp;

  f32x4 acc[FM][FN];
  f32x4 z4 = {0.f,0.f,0.f,0.f};
  #pragma unroll
  for (int m=0;m<FM;m++)
    #pragma unroll
    for (int n=0;n<FN;n++) acc[m][n] = z4;

  auto stage = [&](float4* ar, float4* br, int kk, char* buf){
    if constexpr (AF32) f32_load<BM,BK,THREADS,NC8A>(Af, m0, lda, kk, ar, tid);
    else                stage_lds<BM,BK,THREADS>(Ah, m0, lda, kk, buf, tid);
    if constexpr (BF32) f32_load<BN,BK,THREADS,NC8B>(Bf, n0, ldb, kk, br, tid);
    else                stage_lds<BN,BK,THREADS>(Bh, n0, ldb, kk, buf + BM*ROWB, tid);
  };
  auto wrt = [&](const float4* ar, const float4* br, char* buf, int kk){
    if constexpr (AF32) f32_write<BM,BK,THREADS,NC8A,false,AWB>(ar, buf, Awb, m0, lda, kk, tid);
    if constexpr (BF32) f32_write<BN,BK,THREADS,NC8B,BRELU,false>(br, buf + BM*ROWB, (unsigned short*)0, n0, ldb, kk, tid);
  };
  auto compute = [&](const char* buf){
    const char* bA = buf;
    const char* bB = buf + BM*ROWB;
    #pragma unroll
    for (int ks=0;ks<KS;ks++){
      s16x8 av[FM], bv[FN];
      #pragma unroll
      for (int m=0;m<FM;m++){
        int r = wrr*WM + m*16 + (lane&15);
        int s = (ks*4 + (lane>>4)) ^ ((r>>RSH)&SLM);
        av[m] = *(const s16x8*)(bA + r*ROWB + s*16);
      }
      #pragma unroll
      for (int n=0;n<FN;n++){
        int r = wcc*WN + n*16 + (lane&15);
        int s = (ks*4 + (lane>>4)) ^ ((r>>RSH)&SLM);
        bv[n] = *(const s16x8*)(bB + r*ROWB + s*16);
      }
      #pragma unroll
      for (int m=0;m<FM;m++)
        #pragma unroll
        for (int n=0;n<FN;n++)
          acc[m][n] = __builtin_amdgcn_mfma_f32_16x16x32_bf16(av[m], bv[n], acc[m][n], 0, 0, 0);
    }
  };

  char* bc = smem;
  char* bn_ = smem + TBYTES;
  char* bf_ = smem + 2*TBYTES;

  float4 a0[MA], a1[MA], b0[MB], b1[MB];

  stage(a0, b0, kbeg,      bc);
  stage(a1, b1, kbeg + BK, bn_);

  auto iterate = [&](int t, float4* ar, float4* br){
    if (t == 0)            vmwait<L>();
    else if (t >= nk-1)    vmwait<NS>();
    else                   vmwait<L+NS>();
    if constexpr (AF32 || BF32){
      wrt(ar, br, bc, kbeg + t*BK);
      lgkm0();
    }
    pipebar();
    if (t+2 < nk) stage(ar, br, kbeg + (t+2)*BK, bf_);
    compute(bc);
    pipebar();
    char* tmp = bc; bc = bn_; bn_ = bf_; bf_ = tmp;
  };

  for (int t = 0; t < nk; t += 2){
    iterate(t,   a0, b0);
    iterate(t+1, a1, b1);
  }

  // epilogue: C/D layout (verified m89): col=lane&15, row=(lane>>4)*4+reg
  if constexpr (ATOMIC) {
    float* Cf = (float*)Cp;
    #pragma unroll
    for (int m=0;m<FM;m++)
      #pragma unroll
      for (int n=0;n<FN;n++)
        #pragma unroll
        for (int r=0;r<4;r++){
          int row = m0 + wrr*WM + m*16 + (lane>>4)*4 + r;
          int col = n0 + wcc*WN + n*16 + (lane&15);
          atomicAdd(Cf + (size_t)row*ldc + col, acc[m][n][r]);
        }
  } else {
    unsigned short* Ch = (unsigned short*)Cp;
    #pragma unroll
    for (int m=0;m<FM;m++)
      #pragma unroll
      for (int n=0;n<FN;n++)
        #pragma unroll
        for (int r=0;r<4;r++){
          int row = m0 + wrr*WM + m*16 + (lane>>4)*4 + r;
          int col = n0 + wcc*WN + n*16 + (lane&15);
          Ch[(size_t)row*ldc + col] = f2bf(acc[m][n][r]);
        }
  }
}

// ---------------- emb finalize: f32 out, bf16 copy, row sq-sums ----------------
__global__ void k_emb_fin(const float* __restrict__ acc, float* __restrict__ emb_out,
                          unsigned short* __restrict__ embb, float* __restrict__ sq){
  int idx = blockIdx.x*256 + threadIdx.x;
  float v = acc[idx];
  emb_out[idx] = v;
  unsigned short ub = f2bf(v);
  embb[idx] = ub;
  float x = bf2f(ub);
  float s = x*x;
  #pragma unroll
  for (int off=32; off>0; off>>=1) s += __shfl_xor(s, off, 64);
  if ((threadIdx.x & 63)==0) sq[idx>>6] = s;
}

// ---------------- distance softmax (G = emb@emb^T tiles via MFMA) ----------------
template<int PASS>
__global__ __launch_bounds__(256)
void k_dist(const unsigned short* __restrict__ embb, const float* __restrict__ sq,
            float* __restrict__ S, float* __restrict__ out)
{
  constexpr int ROWB = 128, SLM = 7;
  __shared__ char smem[2*128*128];
  char* bufA = smem;
  char* bufB = smem + 128*ROWB;
  const int tid=threadIdx.x, lane=tid&63, wid=tid>>6;
  const int wrr = wid>>1, wcc = wid&1;
  const int i0 = blockIdx.y*128, j0 = blockIdx.x*128;

  #pragma unroll
  for (int i=0;i<4;i++){
    int u = tid + i*256;
    int r = u>>3, c = u&7;
    int byte = r*ROWB + ((c^(r&SLM))*16);
    *(int4*)(bufA+byte) = *(const int4*)(embb + (size_t)(i0+r)*64 + c*8);
    *(int4*)(bufB+byte) = *(const int4*)(embb + (size_t)(j0+r)*64 + c*8);
  }
  __syncthreads();

  f32x4 acc[4][4];
  f32x4 z4 = {0.f,0.f,0.f,0.f};
  #pragma unroll
  for (int m=0;m<4;m++)
    #pragma unroll
    for (int n=0;n<4;n++) acc[m][n]=z4;

  #pragma unroll
  for (int ks=0;ks<2;ks++){
    s16x8 av[4], bv[4];
    #pragma unroll
    for (int m=0;m<4;m++){
      int r = wrr*64 + m*16 + (lane&15);
      int slot = (ks*4 + (lane>>4)) ^ (r&SLM);
      av[m] = *(const s16x8*)(bufA + r*ROWB + slot*16);
    }
    #pragma unroll
    for (int n=0;n<4;n++){
      int r = wcc*64 + n*16 + (lane&15);
      int slot = (ks*4 + (lane>>4)) ^ (r&SLM);
      bv[n] = *(const s16x8*)(bufB + r*ROWB + slot*16);
    }
    #pragma unroll
    for (int m=0;m<4;m++)
      #pragma unroll
      for (int n=0;n<4;n++)
        acc[m][n] = __builtin_amdgcn_mfma_f32_16x16x32_bf16(av[m], bv[n], acc[m][n], 0, 0, 0);
  }

  float sqj[4];
  #pragma unroll
  for (int n=0;n<4;n++) sqj[n] = sq[j0 + wcc*64 + n*16 + (lane&15)];

  #pragma unroll
  for (int m=0;m<4;m++){
    #pragma unroll
    for (int r=0;r<4;r++){
      int row = i0 + wrr*64 + m*16 + (lane>>4)*4 + r;
      float sqi = sq[row];
      if constexpr (PASS==1){
        float v = 0.f;
        #pragma unroll
        for (int n=0;n<4;n++){
          float d = fmaxf(sqi + sqj[n] - 2.f*acc[m][n][r], 0.f);
          v += __expf(-d);
        }
        #pragma unroll
        for (int off=1; off<16; off<<=1) v += __shfl_xor(v, off, 64);
        if ((lane&15)==0) atomicAdd(S+row, v);
      } else {
        float inv = 1.0f / S[row];
        #pragma unroll
        for (int n=0;n<4;n++){
          int col = j0 + wcc*64 + n*16 + (lane&15);
          float d = fmaxf(sqi + sqj[n] - 2.f*acc[m][n][r], 0.f);
          out[(size_t)row*8192 + col] = __expf(-d)*inv + 1e-10f;
        }
      }
    }
  }
}

// ---------------- host launch ----------------
extern "C" void kernel_launch(void* const* d_in, const int* in_sizes, int n_in,
                              void* d_out, int out_size, void* d_ws, size_t ws_size,
                              hipStream_t stream)
{
  const float* xi = (const float*)d_in[0];   // [8192,512]
  const float* F  = (const float*)d_in[1];   // [8192,8192]
  const float* w1 = (const float*)d_in[2];   // [512,256]
  const float* w2 = (const float*)d_in[3];   // [256,64]
  float* out = (float*)d_out;
  float* emb_out = out;                      // 8192*64
  float* recons  = out + (size_t)8192*64;    // 8192*8192

  // F-bf16 (written by G2' as a side effect) lives in the recons region of
  // d_out — scratch until k_dist<2> overwrites every element at the end.
  unsigned short* Fb = (unsigned short*)recons;

  char* ws = (char*)d_ws;
  size_t off = 0;
  auto alloc = [&](size_t bytes)->char*{ char* p = ws + off; off += (bytes + 255) & ~(size_t)255; return p; };
  unsigned short* w1t  = (unsigned short*)alloc((size_t)256*512*2);
  unsigned short* w2t  = (unsigned short*)alloc((size_t)64*256*2);
  unsigned short* t1t  = (unsigned short*)alloc((size_t)256*8192*2);
  unsigned short* t2t  = (unsigned short*)alloc((size_t)64*8192*2);
  unsigned short* embb = (unsigned short*)alloc((size_t)8192*64*2);
  float* sq    = (float*)alloc((size_t)8192*4);
  char* zbase = ws + off;
  float* h_acc   = (float*)alloc((size_t)8192*256*4);
  float* emb_acc = (float*)alloc((size_t)8192*64*4);
  float* S       = (float*)alloc((size_t)8192*4);
  size_t zbytes = (size_t)((ws + off) - zbase);

  hipMemsetAsync(zbase, 0, zbytes, stream);

  k_prep<<<dim3((512*256 + 256*64)/256), 256, 0, stream>>>(w1, w2, w1t, w2t);

  // G1: t1t[256,8192] = w1t[256,512] @ xi(f32)^T   (256 blocks; BF32)
  k_gemm<128,64,64,2,2,false,true,false,false,false><<<dim3(128,2,1),256,0,stream>>>(
      w1t, xi, t1t, nullptr, 512, 512, 8192, 512);

  // G2': h_acc[8192,256] += F(f32) @ t1t^T ; writes Fb bf16 (AWB).
  //      BN=256 -> F read once; split-K=8 -> 512 blocks, 2/CU.
  k_gemm<128,256,32,2,4,true,false,true,false,true><<<dim3(1,64,8),512,0,stream>>>(
      F, t1t, h_acc, Fb, 8192, 8192, 256, 1024);

  // G3: t2t[64,8192] = w2t[64,256] @ relu(h_acc f32)^T   (128 blocks; BF32+RELU)
  k_gemm<64,64,64,2,2,false,true,false,true,false><<<dim3(128,1,1),256,0,stream>>>(
      w2t, h_acc, t2t, nullptr, 256, 256, 8192, 256);

  // G4: emb_acc[8192,64] += Fb(bf16) @ t2t^T   (split-K=8, 512 blocks)
  k_gemm<128,64,64,2,2,false,false,true,false,false><<<dim3(1,64,8),256,0,stream>>>(
      Fb, t2t, emb_acc, nullptr, 8192, 8192, 64, 1024);

  k_emb_fin<<<dim3(8192*64/256),256,0,stream>>>(emb_acc, emb_out, embb, sq);

  k_dist<1><<<dim3(64,64),256,0,stream>>>(embb, sq, S, recons);
  k_dist<2><<<dim3(64,64),256,0,stream>>>(embb, sq, S, recons);
}

// Round 7
// 348.080 us; speedup vs baseline: 1.0784x; 1.0784x over previous
//
#include <hip/hip_runtime.h>

typedef short s16x8 __attribute__((ext_vector_type(8)));
typedef float f32x4 __attribute__((ext_vector_type(4)));
typedef unsigned int u32;

#define DEV static __device__ __forceinline__

DEV unsigned short f2bf(float x){
  u32 u = __builtin_bit_cast(u32, x);
  return (unsigned short)((u + 0x7FFFu + ((u >> 16) & 1u)) >> 16);
}
DEV float bf2f(unsigned short h){ u32 u = ((u32)h) << 16; return __builtin_bit_cast(float, u); }
DEV u32 pack2(float a, float b){ return (u32)f2bf(a) | ((u32)f2bf(b) << 16); }

DEV void gld16(const void* g, void* l){
  __builtin_amdgcn_global_load_lds((const __attribute__((address_space(1))) u32*)g,
                                   (__attribute__((address_space(3))) u32*)l, 16, 0, 0);
}

// counted vmcnt wait (T4)
template<int N> DEV void vmwait(){
  static_assert(N>=0 && N<=8, "vmcnt range");
  if constexpr (N==0) asm volatile("s_waitcnt vmcnt(0)" ::: "memory");
  else if constexpr (N==1) asm volatile("s_waitcnt vmcnt(1)" ::: "memory");
  else if constexpr (N==2) asm volatile("s_waitcnt vmcnt(2)" ::: "memory");
  else if constexpr (N==3) asm volatile("s_waitcnt vmcnt(3)" ::: "memory");
  else if constexpr (N==4) asm volatile("s_waitcnt vmcnt(4)" ::: "memory");
  else if constexpr (N==5) asm volatile("s_waitcnt vmcnt(5)" ::: "memory");
  else if constexpr (N==6) asm volatile("s_waitcnt vmcnt(6)" ::: "memory");
  else if constexpr (N==7) asm volatile("s_waitcnt vmcnt(7)" ::: "memory");
  else                     asm volatile("s_waitcnt vmcnt(8)" ::: "memory");
}
DEV void pipebar(){
  __builtin_amdgcn_sched_barrier(0);
  __builtin_amdgcn_s_barrier();
  __builtin_amdgcn_sched_barrier(0);
}

// ---------------- f32 -> bf16 streaming convert ----------------
__global__ void k_cvt(const float* __restrict__ src, unsigned short* __restrict__ dst, long n4){
  long i = (long)blockIdx.x*256 + threadIdx.x;
  long stride = (long)gridDim.x*256;
  for (; i < n4; i += stride){
    float4 v = ((const float4*)src)[i];
    int2 p; p.x = (int)pack2(v.x, v.y); p.y = (int)pack2(v.z, v.w);
    ((int2*)dst)[i] = p;
  }
}

// ---------------- prep: w1,w2 transpose->bf16 ----------------
__global__ void k_prep(const float* __restrict__ w1, const float* __restrict__ w2,
                       unsigned short* __restrict__ w1t, unsigned short* __restrict__ w2t){
  int idx = blockIdx.x*256 + threadIdx.x;
  if (idx < 512*256){ int r=idx/256, c=idx%256; w1t[(size_t)c*512 + r] = f2bf(w1[idx]); }
  else { int j = idx - 512*256; if (j < 256*64){ int r=j/64, c=j%64; w2t[(size_t)c*256 + r] = f2bf(w2[j]); } }
}

// ------- bf16 staging: global_load_lds 16B, swizzle on GLOBAL src (rule 21) -------
// physical slot s of row r holds source k-chunk s ^ SW(r), SW(r)=(r>>RSH)&SLM.
// RSH=1 for 4-slot rows (BK=32) -> read banks split on r&1 (free 2-way);
// RSH=0 for 8-slot rows (BK=64) -> lanes r,r+8 share bank (free 2-way).
template<int ROWS,int BK,int THREADS>
DEV void stage_lds(const unsigned short* __restrict__ src, int row0, int ld,
                   int kk, char* lds, int tid){
  constexpr int SLOTS = BK/8, SLM = SLOTS-1, RPC = 64/SLOTS;
  constexpr int RSH = (SLOTS==4) ? 1 : 0;
  constexpr int NCH = ROWS*BK*2/1024;
  constexpr int NW = THREADS/64, NI = NCH/NW;
  static_assert(NI*NW==NCH, "chunk exact");
  const int lane = tid & 63, wid = tid >> 6;
  #pragma unroll
  for (int i=0;i<NI;i++){
    int c = i*NW + wid;
    int r = c*RPC + lane/SLOTS;
    int s = lane & SLM;
    int ks = s ^ ((r>>RSH)&SLM);
    gld16(src + (size_t)(row0+r)*ld + kk + ks*8, lds + c*1024);
  }
}

// ---------------- pure-bf16 pipelined GEMM: C[M,N] = A[M,K] @ Bt[N,K]^T ----------------
// T3+T4: 3 LDS buffers, 2 tiles in flight, counted vmcnt, raw barriers.
// PART: store f32 partial tile to Cp + blockIdx.z*pstride (no atomics).
template<int BM,int BN,int BK,int WR,int WC,bool PART>
__global__ __launch_bounds__(WR*WC*64, (WR*WC>=8)?4:2)
void k_gemm(const unsigned short* __restrict__ A, const unsigned short* __restrict__ B,
            void* __restrict__ Cp, int lda, int ldb, int ldc, int kchunk, long pstride)
{
  constexpr int THREADS = WR*WC*64;
  constexpr int ROWB = BK*2, SLOTS = BK/8, SLM = SLOTS-1;
  constexpr int RSH = (SLOTS==4) ? 1 : 0;
  constexpr int TBYTES = (BM+BN)*ROWB;
  constexpr int WM = BM/WR, WN = BN/WC;
  constexpr int FM = WM/16, FN = WN/16, KS = BK/32;
  constexpr int LA = BM*ROWB/1024/(THREADS/64);
  constexpr int LB = BN*ROWB/1024/(THREADS/64);
  constexpr int L  = LA + LB;

  __shared__ char smem[3*TBYTES];

  const int tid = threadIdx.x, lane = tid & 63;
  const int wid = tid >> 6, wrr = wid / WC, wcc = wid % WC;
  const int m0 = blockIdx.y * BM, n0 = blockIdx.x * BN;
  const int kbeg = blockIdx.z * kchunk, nk = kchunk / BK;

  f32x4 acc[FM][FN];
  f32x4 z4 = {0.f,0.f,0.f,0.f};
  #pragma unroll
  for (int m=0;m<FM;m++)
    #pragma unroll
    for (int n=0;n<FN;n++) acc[m][n] = z4;

  auto stage = [&](int kk, char* buf){
    stage_lds<BM,BK,THREADS>(A, m0, lda, kk, buf, tid);
    stage_lds<BN,BK,THREADS>(B, n0, ldb, kk, buf + BM*ROWB, tid);
  };
  auto compute = [&](const char* buf){
    const char* bA = buf;
    const char* bB = buf + BM*ROWB;
    #pragma unroll
    for (int ks=0;ks<KS;ks++){
      s16x8 av[FM], bv[FN];
      #pragma unroll
      for (int m=0;m<FM;m++){
        int r = wrr*WM + m*16 + (lane&15);
        int s = (ks*4 + (lane>>4)) ^ ((r>>RSH)&SLM);
        av[m] = *(const s16x8*)(bA + r*ROWB + s*16);
      }
      #pragma unroll
      for (int n=0;n<FN;n++){
        int r = wcc*WN + n*16 + (lane&15);
        int s = (ks*4 + (lane>>4)) ^ ((r>>RSH)&SLM);
        bv[n] = *(const s16x8*)(bB + r*ROWB + s*16);
      }
      #pragma unroll
      for (int m=0;m<FM;m++)
        #pragma unroll
        for (int n=0;n<FN;n++)
          acc[m][n] = __builtin_amdgcn_mfma_f32_16x16x32_bf16(av[m], bv[n], acc[m][n], 0, 0, 0);
    }
  };

  char* bc  = smem;
  char* bn_ = smem + TBYTES;
  char* bf_ = smem + 2*TBYTES;

  stage(kbeg, bc);
  stage(kbeg + BK, bn_);

  for (int t=0; t<nk; t++){
    if (t+1 < nk) vmwait<L>();   // tile t landed; t+1's L loads stay in flight
    else          vmwait<0>();
    pipebar();
    if (t+2 < nk) stage(kbeg + (t+2)*BK, bf_);
    compute(bc);
    pipebar();
    char* tmp = bc; bc = bn_; bn_ = bf_; bf_ = tmp;
  }

  // epilogue: C/D layout (verified m89): col=lane&15, row=(lane>>4)*4+reg
  if constexpr (PART) {
    float* Cf = (float*)Cp + (size_t)blockIdx.z * pstride;
    #pragma unroll
    for (int m=0;m<FM;m++)
      #pragma unroll
      for (int n=0;n<FN;n++)
        #pragma unroll
        for (int r=0;r<4;r++){
          int row = m0 + wrr*WM + m*16 + (lane>>4)*4 + r;
          int col = n0 + wcc*WN + n*16 + (lane&15);
          Cf[(size_t)row*ldc + col] = acc[m][n][r];
        }
  } else {
    unsigned short* Ch = (unsigned short*)Cp;
    #pragma unroll
    for (int m=0;m<FM;m++)
      #pragma unroll
      for (int n=0;n<FN;n++)
        #pragma unroll
        for (int r=0;r<4;r++){
          int row = m0 + wrr*WM + m*16 + (lane>>4)*4 + r;
          int col = n0 + wcc*WN + n*16 + (lane&15);
          Ch[(size_t)row*ldc + col] = f2bf(acc[m][n][r]);
        }
  }
}

// ---------------- h reduce: h = relu(sum_z h_part[z]) -> bf16 ----------------
__global__ void k_hred(const float* __restrict__ hp, unsigned short* __restrict__ h){
  const long N = (long)8192*256/4;           // float4 count
  long i = (long)blockIdx.x*256 + threadIdx.x;
  if (i >= N) return;
  float4 s = ((const float4*)hp)[i];
  #pragma unroll
  for (int z=1; z<8; z++){
    float4 v = ((const float4*)(hp + (size_t)z*8192*256))[i];
    s.x+=v.x; s.y+=v.y; s.z+=v.z; s.w+=v.w;
  }
  int2 p;
  p.x = (int)pack2(fmaxf(s.x,0.f), fmaxf(s.y,0.f));
  p.y = (int)pack2(fmaxf(s.z,0.f), fmaxf(s.w,0.f));
  ((int2*)h)[i] = p;
}

// ---------------- emb finalize: sum e_part -> f32 out, bf16 copy, row sq-sums ------
__global__ void k_emb_fin(const float* __restrict__ ep, float* __restrict__ emb_out,
                          unsigned short* __restrict__ embb, float* __restrict__ sq){
  int idx = blockIdx.x*256 + threadIdx.x;   // 8192*64 threads, 64 lanes == one row
  float v = 0.f;
  #pragma unroll
  for (int z=0; z<8; z++) v += ep[(size_t)z*8192*64 + idx];
  emb_out[idx] = v;
  unsigned short ub = f2bf(v);
  embb[idx] = ub;
  float x = bf2f(ub);
  float s = x*x;
  #pragma unroll
  for (int off=32; off>0; off>>=1) s += __shfl_xor(s, off, 64);
  if ((threadIdx.x & 63)==0) sq[idx>>6] = s;
}

// ---------------- distance softmax (G = emb@emb^T tiles via MFMA) ----------------
template<int PASS>
__global__ __launch_bounds__(256)
void k_dist(const unsigned short* __restrict__ embb, const float* __restrict__ sq,
            float* __restrict__ S, float* __restrict__ out)
{
  constexpr int ROWB = 128, SLM = 7;
  __shared__ char smem[2*128*128];
  char* bufA = smem;
  char* bufB = smem + 128*ROWB;
  const int tid=threadIdx.x, lane=tid&63, wid=tid>>6;
  const int wrr = wid>>1, wcc = wid&1;
  const int i0 = blockIdx.y*128, j0 = blockIdx.x*128;

  #pragma unroll
  for (int i=0;i<4;i++){
    int u = tid + i*256;
    int r = u>>3, c = u&7;
    int byte = r*ROWB + ((c^(r&SLM))*16);
    *(int4*)(bufA+byte) = *(const int4*)(embb + (size_t)(i0+r)*64 + c*8);
    *(int4*)(bufB+byte) = *(const int4*)(embb + (size_t)(j0+r)*64 + c*8);
  }
  __syncthreads();

  f32x4 acc[4][4];
  f32x4 z4 = {0.f,0.f,0.f,0.f};
  #pragma unroll
  for (int m=0;m<4;m++)
    #pragma unroll
    for (int n=0;n<4;n++) acc[m][n]=z4;

  #pragma unroll
  for (int ks=0;ks<2;ks++){
    s16x8 av[4], bv[4];
    #pragma unroll
    for (int m=0;m<4;m++){
      int r = wrr*64 + m*16 + (lane&15);
      int slot = (ks*4 + (lane>>4)) ^ (r&SLM);
      av[m] = *(const s16x8*)(bufA + r*ROWB + slot*16);
    }
    #pragma unroll
    for (int n=0;n<4;n++){
      int r = wcc*64 + n*16 + (lane&15);
      int slot = (ks*4 + (lane>>4)) ^ (r&SLM);
      bv[n] = *(const s16x8*)(bufB + r*ROWB + slot*16);
    }
    #pragma unroll
    for (int m=0;m<4;m++)
      #pragma unroll
      for (int n=0;n<4;n++)
        acc[m][n] = __builtin_amdgcn_mfma_f32_16x16x32_bf16(av[m], bv[n], acc[m][n], 0, 0, 0);
  }

  float sqj[4];
  #pragma unroll
  for (int n=0;n<4;n++) sqj[n] = sq[j0 + wcc*64 + n*16 + (lane&15)];

  #pragma unroll
  for (int m=0;m<4;m++){
    #pragma unroll
    for (int r=0;r<4;r++){
      int row = i0 + wrr*64 + m*16 + (lane>>4)*4 + r;
      float sqi = sq[row];
      if constexpr (PASS==1){
        float v = 0.f;
        #pragma unroll
        for (int n=0;n<4;n++){
          float d = fmaxf(sqi + sqj[n] - 2.f*acc[m][n][r], 0.f);
          v += __expf(-d);
        }
        #pragma unroll
        for (int off=1; off<16; off<<=1) v += __shfl_xor(v, off, 64);
        if ((lane&15)==0) atomicAdd(S+row, v);
      } else {
        float inv = 1.0f / S[row];
        #pragma unroll
        for (int n=0;n<4;n++){
          int col = j0 + wcc*64 + n*16 + (lane&15);
          float d = fmaxf(sqi + sqj[n] - 2.f*acc[m][n][r], 0.f);
          out[(size_t)row*8192 + col] = __expf(-d)*inv + 1e-10f;
        }
      }
    }
  }
}

// ---------------- host launch ----------------
extern "C" void kernel_launch(void* const* d_in, const int* in_sizes, int n_in,
                              void* d_out, int out_size, void* d_ws, size_t ws_size,
                              hipStream_t stream)
{
  const float* xi = (const float*)d_in[0];   // [8192,512]
  const float* F  = (const float*)d_in[1];   // [8192,8192]
  const float* w1 = (const float*)d_in[2];   // [512,256]
  const float* w2 = (const float*)d_in[3];   // [256,64]
  float* out = (float*)d_out;
  float* emb_out = out;                      // 8192*64
  float* recons  = out + (size_t)8192*64;    // 8192*8192

  // F-bf16 lives in the recons region of d_out (scratch until k_dist<2>
  // overwrites every element at the end).
  unsigned short* Fb = (unsigned short*)recons;

  char* ws = (char*)d_ws;
  size_t off = 0;
  auto alloc = [&](size_t bytes)->char*{ char* p = ws + off; off += (bytes + 255) & ~(size_t)255; return p; };
  unsigned short* w1t  = (unsigned short*)alloc((size_t)256*512*2);
  unsigned short* w2t  = (unsigned short*)alloc((size_t)64*256*2);
  unsigned short* xib  = (unsigned short*)alloc((size_t)8192*512*2);
  unsigned short* t1t  = (unsigned short*)alloc((size_t)256*8192*2);
  unsigned short* t2t  = (unsigned short*)alloc((size_t)64*8192*2);
  unsigned short* h    = (unsigned short*)alloc((size_t)8192*256*2);
  unsigned short* embb = (unsigned short*)alloc((size_t)8192*64*2);
  float* sq     = (float*)alloc((size_t)8192*4);
  float* h_part = (float*)alloc((size_t)8*8192*256*4);   // 64 MB
  float* e_part = (float*)alloc((size_t)8*8192*64*4);    // 16 MB
  float* S      = (float*)alloc((size_t)8192*4);

  hipMemsetAsync(S, 0, (size_t)8192*4, stream);

  k_prep<<<dim3((512*256 + 256*64)/256), 256, 0, stream>>>(w1, w2, w1t, w2t);
  k_cvt<<<dim3(2048),256,0,stream>>>(F,  Fb,  (long)8192*8192/4);
  k_cvt<<<dim3(256), 256,0,stream>>>(xi, xib, (long)8192*512/4);

  // G1: t1t[256,8192] = w1t[256,512] @ xib[8192,512]^T   (256 blocks)
  k_gemm<128,64,64,2,2,false><<<dim3(128,2,1),256,0,stream>>>(
      w1t, xib, t1t, 512, 512, 8192, 512, 0);

  // G2: h_part[z][8192,256] = Fb @ t1t^T  (BN=256 -> F once; split-K=8, 512 blocks)
  k_gemm<128,256,32,2,4,true><<<dim3(1,64,8),512,0,stream>>>(
      Fb, t1t, h_part, 8192, 8192, 256, 1024, (long)8192*256);

  k_hred<<<dim3(2048),256,0,stream>>>(h_part, h);

  // G3: t2t[64,8192] = w2t[64,256] @ h[8192,256]^T   (256 blocks)
  k_gemm<64,32,64,2,2,false><<<dim3(256,1,1),256,0,stream>>>(
      w2t, h, t2t, 256, 256, 8192, 256, 0);

  // G4: e_part[z][8192,64] = Fb @ t2t^T   (split-K=8, 512 blocks)
  k_gemm<128,64,64,2,2,true><<<dim3(1,64,8),256,0,stream>>>(
      Fb, t2t, e_part, 8192, 8192, 64, 1024, (long)8192*64);

  k_emb_fin<<<dim3(8192*64/256),256,0,stream>>>(e_part, emb_out, embb, sq);

  k_dist<1><<<dim3(64,64),256,0,stream>>>(embb, sq, S, recons);
  k_dist<2><<<dim3(64,64),256,0,stream>>>(embb, sq, S, recons);
}